// Round 1
// baseline (319.425 us; speedup 1.0000x reference)
//
#include <hip/hip_runtime.h>
#include <hip/hip_bf16.h>
#include <math.h>

// Problem constants (from reference)
#define B_   64
#define L_   512
#define V_   20000
#define P_   150
#define M_   6
#define KDIM 300
#define NOUT 750          // P_ * (M_-1) used transition scores
#define CWS  752          // padded row stride (16B-aligned float4 rows)
#define NEGF (-1.0e9f)

// GEMM tiling
#define BM 128
#define BN 128
#define BK 16

// Scan chunking
#define TCHUNK 32
#define NCHUNK (L_ / TCHUNK)   // 16
#define WARM   5
#define CS_STRIDE 160

__device__ __forceinline__ float logsigf(float x) {
    // matches jax: -softplus(-x) = min(x,0) - log1p(exp(-|x|))
    return fminf(x, 0.f) - log1pf(expf(-fabsf(x)));
}

// K1: cw[v][n] = max(logsig(diags[dpm(n)] . emb[:,v] + bias[dpm(n)]), logsig(wild[n]))
// where n = p*5+m, dpm(n) = (n/5)*6 + n%5
__global__ __launch_bounds__(256) void k1_gemm_cw(
    const float* __restrict__ emb,     // [300][20000]
    const float* __restrict__ diags,   // [900][300]
    const float* __restrict__ bias,    // [900]
    const float* __restrict__ wildc,   // [150][5]
    float* __restrict__ cw)            // [20000][752]
{
    __shared__ float As[BK][BM];       // emb tile [k][v]
    __shared__ float Bs[BN][BK + 4];   // diags tile [n][k], padded

    const int tid = threadIdx.x;
    const int v0 = blockIdx.x * BM;
    const int n0 = blockIdx.y * BN;
    const int tx = tid & 15;           // v group (8 v's)
    const int ty = tid >> 4;           // n group (8 n's)

    float acc[8][8];
    #pragma unroll
    for (int i = 0; i < 8; ++i)
        #pragma unroll
        for (int j = 0; j < 8; ++j) acc[i][j] = 0.f;

    // A staging: 2 float4 per thread
    const int a_k = tid >> 4;          // 0..15
    const int a_v = (tid & 15) * 8;
    // B staging: 2 float4 per thread (128 rows x 4 f4/row = 512 f4)
    const int q0   = tid * 2;
    const int b_n0 = q0 >> 2;
    const int b_k0 = (q0 & 3) * 4;
    const int b_n1 = (q0 + 1) >> 2;
    const int b_k1 = ((q0 + 1) & 3) * 4;

    int  brow0, brow1;
    bool bval0, bval1;
    {
        int n = n0 + b_n0;
        bval0 = (n < NOUT);
        brow0 = bval0 ? ((n / 5) * 6 + (n % 5)) : 0;
        n = n0 + b_n1;
        bval1 = (n < NOUT);
        brow1 = bval1 ? ((n / 5) * 6 + (n % 5)) : 0;
    }

    for (int k0 = 0; k0 < KDIM; k0 += BK) {
        // stage A (zero-fill K tail / V tail)
        {
            float4 f0 = {0,0,0,0}, f1 = {0,0,0,0};
            int k = k0 + a_k;
            if (k < KDIM) {
                const float* src = emb + (size_t)k * V_ + v0 + a_v;
                if (v0 + a_v + 3 < V_) f0 = *(const float4*)src;
                if (v0 + a_v + 7 < V_) f1 = *(const float4*)(src + 4);
            }
            *(float4*)&As[a_k][a_v]     = f0;
            *(float4*)&As[a_k][a_v + 4] = f1;
        }
        // stage B
        {
            float4 f = {0,0,0,0};
            if (bval0 && (k0 + b_k0 + 3 < KDIM))
                f = *(const float4*)(diags + (size_t)brow0 * KDIM + k0 + b_k0);
            *(float4*)&Bs[b_n0][b_k0] = f;
            float4 g = {0,0,0,0};
            if (bval1 && (k0 + b_k1 + 3 < KDIM))
                g = *(const float4*)(diags + (size_t)brow1 * KDIM + k0 + b_k1);
            *(float4*)&Bs[b_n1][b_k1] = g;
        }
        __syncthreads();
        #pragma unroll
        for (int k = 0; k < BK; ++k) {
            float4 a0 = *(const float4*)&As[k][tx * 4];
            float4 a1 = *(const float4*)&As[k][64 + tx * 4];
            float av[8] = {a0.x, a0.y, a0.z, a0.w, a1.x, a1.y, a1.z, a1.w};
            float bv[8];
            #pragma unroll
            for (int j = 0; j < 8; ++j) bv[j] = Bs[ty * 8 + j][k];
            #pragma unroll
            for (int i = 0; i < 8; ++i)
                #pragma unroll
                for (int j = 0; j < 8; ++j)
                    acc[i][j] = fmaf(av[i], bv[j], acc[i][j]);
        }
        __syncthreads();
    }

    // epilogue: + bias, logsigmoid, max with logsig(wild), store
    float biasv[8], lwv[8];
    #pragma unroll
    for (int j = 0; j < 8; ++j) {
        int n  = n0 + ty * 8 + j;
        int nc = (n < NOUT) ? n : 0;
        int pm = (nc / 5) * 6 + (nc % 5);
        biasv[j] = bias[pm];
        lwv[j]   = logsigf(wildc[nc]);
    }
    #pragma unroll
    for (int i = 0; i < 8; ++i) {
        int v = v0 + ((i < 4) ? (tx * 4 + i) : (64 + tx * 4 + (i - 4)));
        if (v >= V_) continue;
        float r[8];
        #pragma unroll
        for (int j = 0; j < 8; ++j)
            r[j] = fmaxf(logsigf(acc[i][j] + biasv[j]), lwv[j]);
        float* dst = cw + (size_t)v * CWS + n0 + ty * 8;
        // writes into 750..751 pad are harmless (never read)
        if (n0 + ty * 8     < NOUT) *(float4*)dst       = make_float4(r[0], r[1], r[2], r[3]);
        if (n0 + ty * 8 + 4 < NOUT) *(float4*)(dst + 4) = make_float4(r[4], r[5], r[6], r[7]);
    }
}

// K2: chunked Viterbi-style scan. hid[0]=0 always => hid[m] is an m-token window
// sum, so a chunk only needs WARM=5 warm-up tokens for exact values.
__global__ __launch_bounds__(192) void k2_scan(
    const int* __restrict__ docs,      // [64][512]
    const int* __restrict__ doc_lens,  // [64]
    const float* __restrict__ cw,      // [20000][752]
    float* __restrict__ cs)            // [64][16][160] chunk maxima
{
    const int ci = blockIdx.x;
    const int b  = blockIdx.y;
    const int t0 = ci * TCHUNK;
    const int ts = (t0 >= WARM) ? (t0 - WARM) : 0;
    const int dl = doc_lens[b];
    const int te = min(t0 + TCHUNK, dl);
    const int nt = te - ts;

    __shared__ int toks[TCHUNK + WARM];
    if (threadIdx.x < TCHUNK + WARM) {
        int t = ts + threadIdx.x;
        toks[threadIdx.x] = docs[b * L_ + min(t, L_ - 1)];
    }
    __syncthreads();

    const int p = threadIdx.x;
    float sc = NEGF;
    if (p < P_) {
        const float* basep = cw + p * 5;
        const int e = (p < 50) ? 3 : (p < 100) ? 4 : 5;
        float h1 = NEGF, h2 = NEGF, h3 = NEGF, h4 = NEGF, h5 = NEGF;
        const int warm_n = t0 - ts;
        #pragma unroll 4
        for (int i = 0; i < nt; ++i) {
            const float* cp = basep + (size_t)toks[i] * CWS;
            float c0 = cp[0], c1 = cp[1], c2 = cp[2], c3 = cp[3], c4 = cp[4];
            h5 = h4 + c4;
            h4 = h3 + c3;
            h3 = h2 + c2;
            h2 = h1 + c1;
            h1 = c0;                       // h0 = 0 always
            if (i >= warm_n) {
                float esv = (e == 3) ? h3 : (e == 4) ? h4 : h5;
                sc = fmaxf(sc, esv);
            }
        }
    }
    if (p < P_) cs[(size_t)(b * NCHUNK + ci) * CS_STRIDE + p] = sc;
}

__device__ __forceinline__ float block_sum192(float v, volatile float* red, int tid) {
    #pragma unroll
    for (int off = 32; off > 0; off >>= 1) v += __shfl_down(v, off, 64);
    __syncthreads();                        // protect red[] reuse across calls
    if ((tid & 63) == 0) red[tid >> 6] = v;
    __syncthreads();
    return red[0] + red[1] + red[2];
}

// K3: max over chunks -> exp -> layernorm(P) -> heaviside -> 150->2 matvec
__global__ __launch_bounds__(192) void k3_final(
    const float* __restrict__ cs,
    const float* __restrict__ gamma,
    const float* __restrict__ beta,
    const float* __restrict__ lw,      // [2][150]
    const float* __restrict__ lb,      // [2]
    float* __restrict__ out)           // [64][2]
{
    __shared__ float red[3];
    const int b   = blockIdx.x;
    const int tid = threadIdx.x;
    float s = 0.f;
    if (tid < P_) {
        float m = NEGF;
        const float* row = cs + (size_t)b * NCHUNK * CS_STRIDE + tid;
        #pragma unroll
        for (int ci = 0; ci < NCHUNK; ++ci) m = fmaxf(m, row[ci * CS_STRIDE]);
        s = expf(m);                       // exp(NEG) underflows to 0 like ref
    }
    float mu = block_sum192(s, red, tid) * (1.f / P_);
    float d  = (tid < P_) ? (s - mu) : 0.f;
    float var = block_sum192(d * d, red, tid) * (1.f / P_);
    float bin = 0.f;
    if (tid < P_) {
        float norm = (s - mu) * rsqrtf(var + 1e-5f) * gamma[tid] + beta[tid];
        bin = (norm > 0.f) ? 1.f : 0.f;
    }
    float o0 = block_sum192((tid < P_) ? bin * lw[tid]      : 0.f, red, tid);
    float o1 = block_sum192((tid < P_) ? bin * lw[P_ + tid] : 0.f, red, tid);
    if (tid == 0) {
        out[b * 2 + 0] = o0 + lb[0];
        out[b * 2 + 1] = o1 + lb[1];
    }
}

extern "C" void kernel_launch(void* const* d_in, const int* in_sizes, int n_in,
                              void* d_out, int out_size, void* d_ws, size_t ws_size,
                              hipStream_t stream)
{
    const int*   docs  = (const int*)  d_in[0];
    const int*   dlens = (const int*)  d_in[1];
    const float* emb   = (const float*)d_in[2];
    const float* diags = (const float*)d_in[3];
    const float* bias  = (const float*)d_in[4];
    const float* wildc = (const float*)d_in[5];
    const float* gamma = (const float*)d_in[6];
    const float* beta  = (const float*)d_in[7];
    const float* lw    = (const float*)d_in[8];
    const float* lb    = (const float*)d_in[9];
    float* out = (float*)d_out;

    // workspace: cw (20000*752 f32 = 60.16 MB) then chunk scores (64*16*160 f32)
    float* cw = (float*)d_ws;
    float* cs = cw + (size_t)V_ * CWS;

    dim3 g1((V_ + BM - 1) / BM, (NOUT + BN - 1) / BN);   // 157 x 6
    k1_gemm_cw<<<g1, 256, 0, stream>>>(emb, diags, bias, wildc, cw);

    dim3 g2(NCHUNK, B_);                                 // 16 x 64
    k2_scan<<<g2, 192, 0, stream>>>(docs, dlens, cw, cs);

    k3_final<<<B_, 192, 0, stream>>>(cs, gamma, beta, lw, lb, out);
}

// Round 2
// 284.265 us; speedup vs baseline: 1.1237x; 1.1237x over previous
//
#include <hip/hip_runtime.h>
#include <hip/hip_bf16.h>
#include <math.h>

// Problem constants (from reference)
#define B_   64
#define L_   512
#define V_   20000
#define P_   150
#define M_   6
#define KDIM 300
#define NOUT 750          // P_ * (M_-1) used transition scores
#define CWS  752          // padded row stride (16B-aligned float4 rows)
#define NEGF (-1.0e9f)

// GEMM tiling
#define BM 128
#define BN 128
#define BK 16
#define LDP 132           // LDS row stride (dwords): +4 pad -> all accesses <=2-way

// Scan chunking
#define TCHUNK 32
#define NCHUNK (L_ / TCHUNK)   // 16
#define WARM   5
#define CS_STRIDE 160

__device__ __forceinline__ float logsigf(float x) {
    // matches jax: -softplus(-x) = min(x,0) - log1p(exp(-|x|))
    return fminf(x, 0.f) - log1pf(expf(-fabsf(x)));
}

// K1: cw[v][n] = max(logsig(diags[dpm(n)] . emb[:,v] + bias[dpm(n)]), logsig(wild[n]))
// where n = p*5+m, dpm(n) = (n/5)*6 + n%5
// Both LDS tiles k-major, row stride LDP=132 dwords:
//   As[k][v]: reads b128 @ tx*4  -> 2-way (free); stores b128 -> 2-way
//   Bs[k][n]: reads b128 @ ty*8  -> conflict-free; transpose b32 stores -> 2-way
__global__ __launch_bounds__(256) void k1_gemm_cw(
    const float* __restrict__ emb,     // [300][20000]
    const float* __restrict__ diags,   // [900][300]
    const float* __restrict__ bias,    // [900]
    const float* __restrict__ wildc,   // [150][5]
    float* __restrict__ cw)            // [20000][752]
{
    __shared__ float As[BK][LDP];
    __shared__ float Bs[BK][LDP];

    const int tid = threadIdx.x;
    const int v0 = blockIdx.x * BM;
    const int n0 = blockIdx.y * BN;
    const int tx = tid & 15;           // v group (8 v's)
    const int ty = tid >> 4;           // n group (8 n's)

    float acc[8][8];
    #pragma unroll
    for (int i = 0; i < 8; ++i)
        #pragma unroll
        for (int j = 0; j < 8; ++j) acc[i][j] = 0.f;

    // A staging: thread -> row a_k, 8 consecutive v
    const int a_k = tid >> 4;          // 0..15
    const int a_v = (tid & 15) * 8;
    // B staging: thread pair covers one n-row's 16 k values
    const int b_n   = tid >> 1;        // 0..127
    const int b_kof = (tid & 1) * 8;   // 0 or 8

    int  brow;
    bool bval;
    {
        int n = n0 + b_n;
        bval = (n < NOUT);
        brow = bval ? ((n / 5) * 6 + (n % 5)) : 0;
    }

    for (int k0 = 0; k0 < KDIM; k0 += BK) {
        // stage A (k-major, contiguous rows)
        {
            float4 f0 = {0,0,0,0}, f1 = {0,0,0,0};
            int k = k0 + a_k;
            if (k < KDIM) {
                const float* src = emb + (size_t)k * V_ + v0 + a_v;
                if (v0 + a_v + 3 < V_) f0 = *(const float4*)src;
                if (v0 + a_v + 7 < V_) f1 = *(const float4*)(src + 4);
            }
            *(float4*)&As[a_k][a_v]     = f0;
            *(float4*)&As[a_k][a_v + 4] = f1;
        }
        // stage B: load 8 consecutive k from diags row, transpose into Bs[k][n]
        {
            float4 f = {0,0,0,0}, g = {0,0,0,0};
            if (bval) {
                const float* src = diags + (size_t)brow * KDIM + k0 + b_kof;
                if (k0 + b_kof + 3 < KDIM) f = *(const float4*)src;
                if (k0 + b_kof + 7 < KDIM) g = *(const float4*)(src + 4);
            }
            Bs[b_kof + 0][b_n] = f.x;
            Bs[b_kof + 1][b_n] = f.y;
            Bs[b_kof + 2][b_n] = f.z;
            Bs[b_kof + 3][b_n] = f.w;
            Bs[b_kof + 4][b_n] = g.x;
            Bs[b_kof + 5][b_n] = g.y;
            Bs[b_kof + 6][b_n] = g.z;
            Bs[b_kof + 7][b_n] = g.w;
        }
        __syncthreads();
        #pragma unroll
        for (int k = 0; k < BK; ++k) {
            float4 a0 = *(const float4*)&As[k][tx * 4];
            float4 a1 = *(const float4*)&As[k][64 + tx * 4];
            float4 b0 = *(const float4*)&Bs[k][ty * 8];
            float4 b1 = *(const float4*)&Bs[k][ty * 8 + 4];
            float av[8] = {a0.x, a0.y, a0.z, a0.w, a1.x, a1.y, a1.z, a1.w};
            float bv[8] = {b0.x, b0.y, b0.z, b0.w, b1.x, b1.y, b1.z, b1.w};
            #pragma unroll
            for (int i = 0; i < 8; ++i)
                #pragma unroll
                for (int j = 0; j < 8; ++j)
                    acc[i][j] = fmaf(av[i], bv[j], acc[i][j]);
        }
        __syncthreads();
    }

    // epilogue: + bias, logsigmoid, max with logsig(wild), store
    float biasv[8], lwv[8];
    #pragma unroll
    for (int j = 0; j < 8; ++j) {
        int n  = n0 + ty * 8 + j;
        int nc = (n < NOUT) ? n : 0;
        int pm = (nc / 5) * 6 + (nc % 5);
        biasv[j] = bias[pm];
        lwv[j]   = logsigf(wildc[nc]);
    }
    #pragma unroll
    for (int i = 0; i < 8; ++i) {
        int v = v0 + ((i < 4) ? (tx * 4 + i) : (64 + tx * 4 + (i - 4)));
        if (v >= V_) continue;
        float r[8];
        #pragma unroll
        for (int j = 0; j < 8; ++j)
            r[j] = fmaxf(logsigf(acc[i][j] + biasv[j]), lwv[j]);
        float* dst = cw + (size_t)v * CWS + n0 + ty * 8;
        // writes into 750..751 pad are harmless (never read)
        if (n0 + ty * 8     < NOUT) *(float4*)dst       = make_float4(r[0], r[1], r[2], r[3]);
        if (n0 + ty * 8 + 4 < NOUT) *(float4*)(dst + 4) = make_float4(r[4], r[5], r[6], r[7]);
    }
}

// K2: chunked Viterbi-style scan. hid[0]=0 always => hid[m] is an m-token window
// sum, so a chunk only needs WARM=5 warm-up tokens for exact values.
__global__ __launch_bounds__(192) void k2_scan(
    const int* __restrict__ docs,      // [64][512]
    const int* __restrict__ doc_lens,  // [64]
    const float* __restrict__ cw,      // [20000][752]
    float* __restrict__ cs)            // [64][16][160] chunk maxima
{
    const int ci = blockIdx.x;
    const int b  = blockIdx.y;
    const int t0 = ci * TCHUNK;
    const int ts = (t0 >= WARM) ? (t0 - WARM) : 0;
    const int dl = doc_lens[b];
    const int te = min(t0 + TCHUNK, dl);
    const int nt = te - ts;

    __shared__ int toks[TCHUNK + WARM];
    if (threadIdx.x < TCHUNK + WARM) {
        int t = ts + threadIdx.x;
        toks[threadIdx.x] = docs[b * L_ + min(t, L_ - 1)];
    }
    __syncthreads();

    const int p = threadIdx.x;
    float sc = NEGF;
    if (p < P_) {
        const float* basep = cw + p * 5;
        const int e = (p < 50) ? 3 : (p < 100) ? 4 : 5;
        float h1 = NEGF, h2 = NEGF, h3 = NEGF, h4 = NEGF, h5 = NEGF;
        const int warm_n = t0 - ts;
        #pragma unroll 4
        for (int i = 0; i < nt; ++i) {
            const float* cp = basep + (size_t)toks[i] * CWS;
            float c0 = cp[0], c1 = cp[1], c2 = cp[2], c3 = cp[3], c4 = cp[4];
            h5 = h4 + c4;
            h4 = h3 + c3;
            h3 = h2 + c2;
            h2 = h1 + c1;
            h1 = c0;                       // h0 = 0 always
            if (i >= warm_n) {
                float esv = (e == 3) ? h3 : (e == 4) ? h4 : h5;
                sc = fmaxf(sc, esv);
            }
        }
    }
    if (p < P_) cs[(size_t)(b * NCHUNK + ci) * CS_STRIDE + p] = sc;
}

__device__ __forceinline__ float block_sum192(float v, volatile float* red, int tid) {
    #pragma unroll
    for (int off = 32; off > 0; off >>= 1) v += __shfl_down(v, off, 64);
    __syncthreads();                        // protect red[] reuse across calls
    if ((tid & 63) == 0) red[tid >> 6] = v;
    __syncthreads();
    return red[0] + red[1] + red[2];
}

// K3: max over chunks -> exp -> layernorm(P) -> heaviside -> 150->2 matvec
__global__ __launch_bounds__(192) void k3_final(
    const float* __restrict__ cs,
    const float* __restrict__ gamma,
    const float* __restrict__ beta,
    const float* __restrict__ lw,      // [2][150]
    const float* __restrict__ lb,      // [2]
    float* __restrict__ out)           // [64][2]
{
    __shared__ float red[3];
    const int b   = blockIdx.x;
    const int tid = threadIdx.x;
    float s = 0.f;
    if (tid < P_) {
        float m = NEGF;
        const float* row = cs + (size_t)b * NCHUNK * CS_STRIDE + tid;
        #pragma unroll
        for (int ci = 0; ci < NCHUNK; ++ci) m = fmaxf(m, row[ci * CS_STRIDE]);
        s = expf(m);                       // exp(NEG) underflows to 0 like ref
    }
    float mu = block_sum192(s, red, tid) * (1.f / P_);
    float d  = (tid < P_) ? (s - mu) : 0.f;
    float var = block_sum192(d * d, red, tid) * (1.f / P_);
    float bin = 0.f;
    if (tid < P_) {
        float norm = (s - mu) * rsqrtf(var + 1e-5f) * gamma[tid] + beta[tid];
        bin = (norm > 0.f) ? 1.f : 0.f;
    }
    float o0 = block_sum192((tid < P_) ? bin * lw[tid]      : 0.f, red, tid);
    float o1 = block_sum192((tid < P_) ? bin * lw[P_ + tid] : 0.f, red, tid);
    if (tid == 0) {
        out[b * 2 + 0] = o0 + lb[0];
        out[b * 2 + 1] = o1 + lb[1];
    }
}

extern "C" void kernel_launch(void* const* d_in, const int* in_sizes, int n_in,
                              void* d_out, int out_size, void* d_ws, size_t ws_size,
                              hipStream_t stream)
{
    const int*   docs  = (const int*)  d_in[0];
    const int*   dlens = (const int*)  d_in[1];
    const float* emb   = (const float*)d_in[2];
    const float* diags = (const float*)d_in[3];
    const float* bias  = (const float*)d_in[4];
    const float* wildc = (const float*)d_in[5];
    const float* gamma = (const float*)d_in[6];
    const float* beta  = (const float*)d_in[7];
    const float* lw    = (const float*)d_in[8];
    const float* lb    = (const float*)d_in[9];
    float* out = (float*)d_out;

    // workspace: cw (20000*752 f32 = 60.16 MB) then chunk scores (64*16*160 f32)
    float* cw = (float*)d_ws;
    float* cs = cw + (size_t)V_ * CWS;

    dim3 g1((V_ + BM - 1) / BM, (NOUT + BN - 1) / BN);   // 157 x 6
    k1_gemm_cw<<<g1, 256, 0, stream>>>(emb, diags, bias, wildc, cw);

    dim3 g2(NCHUNK, B_);                                 // 16 x 64
    k2_scan<<<g2, 192, 0, stream>>>(docs, dlens, cw, cs);

    k3_final<<<B_, 192, 0, stream>>>(cs, gamma, beta, lw, lb, out);
}

// Round 3
// 218.182 us; speedup vs baseline: 1.4640x; 1.3029x over previous
//
#include <hip/hip_runtime.h>
#include <hip/hip_bf16.h>
#include <hip/hip_fp16.h>
#include <math.h>

// Problem constants (from reference)
#define B_   64
#define L_   512
#define V_   20000
#define P_   150
#define M_   6
#define KDIM 300
#define NOUT 750          // P_ * (M_-1) used transition scores
#define CWS  752          // padded row stride (16B-aligned float4 rows)
#define NEGF (-1.0e9f)

// f32 fallback GEMM tiling
#define BM 128
#define BN 128
#define BK 16
#define LDP 132

// MFMA path constants
#define KP 320            // K padded to multiple of 16
#define NP 768            // N padded to 6*128
#define SA 1024.0f        // emb scale (keeps lo-split out of fp16 subnormals)
#define SB 16384.0f       // diags scale
#define INV24 (5.9604644775390625e-8f)   // 2^-24

// Scan chunking
#define TCHUNK 32
#define NCHUNK (L_ / TCHUNK)   // 16
#define WARM   5
#define CS_STRIDE 160

typedef _Float16 f16x8 __attribute__((ext_vector_type(8)));
typedef float f32x16 __attribute__((ext_vector_type(16)));

__device__ __forceinline__ float logsigf(float x) {
    // matches jax: -softplus(-x) = min(x,0) - log1p(exp(-|x|))
    return fminf(x, 0.f) - log1pf(expf(-fabsf(x)));
}

// ---------------- MFMA path ----------------

// P1: transpose emb [300][20000] -> fp16 hi/lo splits a1,a2 [20000][320] (k-contig)
__global__ __launch_bounds__(256) void p1_split_a(
    const float* __restrict__ emb,
    ushort* __restrict__ a1, ushort* __restrict__ a2)
{
    __shared__ float T[64][65];
    const int t  = threadIdx.x;
    const int v0 = blockIdx.x * 64;
    const int k0 = blockIdx.y * 64;
    const int kk = t >> 6, vv = t & 63;
    #pragma unroll
    for (int r = 0; r < 16; ++r) {
        int kl = r * 4 + kk;
        int k = k0 + kl, v = v0 + vv;
        float x = 0.f;
        if (k < KDIM && v < V_) x = emb[(size_t)k * V_ + v];
        T[kl][vv] = x;
    }
    __syncthreads();
    const int vv2 = t >> 2, kq = t & 3;
    const int v = v0 + vv2;
    if (v < V_) {
        #pragma unroll
        for (int r = 0; r < 2; ++r) {
            int klb = kq * 16 + r * 8;
            union { ushort u[8]; uint4 q; } H, L;
            #pragma unroll
            for (int j = 0; j < 8; ++j) {
                float x = T[klb + j][vv2] * SA;
                __half h = __float2half_rn(x);
                float rem = x - __half2float(h);
                H.u[j] = __half_as_ushort(h);
                L.u[j] = __half_as_ushort(__float2half_rn(rem));
            }
            size_t idx = (size_t)v * KP + k0 + klb;
            *(uint4*)(a1 + idx) = H.q;
            *(uint4*)(a2 + idx) = L.q;
        }
    }
}

// P2: diags rows (dpm-mapped, scaled) -> fp16 splits b1,b2 [768][320], zero-padded
__global__ __launch_bounds__(64) void p2_split_b(
    const float* __restrict__ diags,
    ushort* __restrict__ b1, ushort* __restrict__ b2)
{
    const int n = blockIdx.x;       // 0..767
    const int t = threadIdx.x;      // 0..63
    const int pm = (n / 5) * 6 + (n % 5);
    #pragma unroll
    for (int j = 0; j < 5; ++j) {
        int k = t + j * 64;
        float x = 0.f;
        if (n < NOUT && k < KDIM) x = diags[(size_t)pm * KDIM + k] * SB;
        __half h = __float2half_rn(x);
        float rem = x - __half2float(h);
        b1[(size_t)n * KP + k] = __half_as_ushort(h);
        b2[(size_t)n * KP + k] = __half_as_ushort(__float2half_rn(rem));
    }
}

// K1 (MFMA): C = a1@b1 + a1@b2 + a2@b1 (fp16 split-f32), epilogue logsig+max+store.
// Tile 128x128, 4 waves (2x2), each wave 2x2 mfma_f32_32x32x16_f16 per product.
// LDS: [sec(a1,a2,b1,b2)][k16][row 128] of 16B blocks = 16 KB.
// Frag reads: lane -> row (lane&31), k16 (lane>>5): 8-lane phases hit distinct banks.
__global__ __launch_bounds__(256) void k1m_gemm(
    const ushort* __restrict__ a1, const ushort* __restrict__ a2,
    const ushort* __restrict__ b1, const ushort* __restrict__ b2,
    const float* __restrict__ bias, const float* __restrict__ wildc,
    float* __restrict__ cw)
{
    __shared__ uint4 sm[4 * 2 * 128];
    const int t    = threadIdx.x;
    const int lane = t & 63;
    const int w    = t >> 6;
    const int wr   = w >> 1, wc = w & 1;
    const int v0   = blockIdx.x * 128;
    const int n0   = blockIdx.y * 128;

    // staging: thread -> (row, k16) covering all 4 sections
    const int sm_row = t >> 1;
    const int sk16   = t & 1;
    const bool aok = (v0 + sm_row) < V_;
    const uint4* gA1 = (const uint4*)a1 + ((size_t)(v0 + sm_row) * KP + sk16 * 8) / 8;
    const uint4* gA2 = (const uint4*)a2 + ((size_t)(v0 + sm_row) * KP + sk16 * 8) / 8;
    const uint4* gB1 = (const uint4*)b1 + ((size_t)(n0 + sm_row) * KP + sk16 * 8) / 8;
    const uint4* gB2 = (const uint4*)b2 + ((size_t)(n0 + sm_row) * KP + sk16 * 8) / 8;

    const int fk16 = lane >> 5;
    const int fm   = lane & 31;
    const int aoff = (0 + fk16) * 128 + wr * 64 + fm;   // a1 section
    const int boff = (4 + fk16) * 128 + wc * 64 + fm;   // b1 section

    f32x16 acc[2][2];
    #pragma unroll
    for (int i = 0; i < 2; ++i)
        #pragma unroll
        for (int j = 0; j < 2; ++j)
            #pragma unroll
            for (int r = 0; r < 16; ++r) acc[i][j][r] = 0.f;

    for (int it = 0; it < KP / 16; ++it) {
        uint4 ra1 = {0,0,0,0}, ra2 = {0,0,0,0};
        if (aok) { ra1 = gA1[it * 2]; ra2 = gA2[it * 2]; }
        uint4 rb1 = gB1[it * 2];
        uint4 rb2 = gB2[it * 2];
        __syncthreads();
        sm[(0 + sk16) * 128 + sm_row] = ra1;
        sm[(2 + sk16) * 128 + sm_row] = ra2;
        sm[(4 + sk16) * 128 + sm_row] = rb1;
        sm[(6 + sk16) * 128 + sm_row] = rb2;
        __syncthreads();
        f16x8 A1[2], A2[2], B1[2], B2[2];
        #pragma unroll
        for (int ri = 0; ri < 2; ++ri) {
            A1[ri] = *(const f16x8*)&sm[aoff + ri * 32];
            A2[ri] = *(const f16x8*)&sm[aoff + 256 + ri * 32];
        }
        #pragma unroll
        for (int cj = 0; cj < 2; ++cj) {
            B1[cj] = *(const f16x8*)&sm[boff + cj * 32];
            B2[cj] = *(const f16x8*)&sm[boff + 256 + cj * 32];
        }
        #pragma unroll
        for (int ri = 0; ri < 2; ++ri)
            #pragma unroll
            for (int cj = 0; cj < 2; ++cj) {
                acc[ri][cj] = __builtin_amdgcn_mfma_f32_32x32x16_f16(A1[ri], B1[cj], acc[ri][cj], 0, 0, 0);
                acc[ri][cj] = __builtin_amdgcn_mfma_f32_32x32x16_f16(A1[ri], B2[cj], acc[ri][cj], 0, 0, 0);
                acc[ri][cj] = __builtin_amdgcn_mfma_f32_32x32x16_f16(A2[ri], B1[cj], acc[ri][cj], 0, 0, 0);
            }
    }

    // epilogue: C/D layout col=lane&31, row=(r&3)+8*(r>>2)+4*(lane>>5)
    float biasv[2], lwv[2]; int ncol[2]; bool nok[2];
    #pragma unroll
    for (int cj = 0; cj < 2; ++cj) {
        int n = n0 + wc * 64 + cj * 32 + fm;
        ncol[cj] = n;
        nok[cj]  = (n < NOUT);
        int nc = nok[cj] ? n : 0;
        int pm = (nc / 5) * 6 + (nc % 5);
        biasv[cj] = bias[pm];
        lwv[cj]   = logsigf(wildc[nc]);
    }
    #pragma unroll
    for (int ri = 0; ri < 2; ++ri) {
        int vbase = v0 + wr * 64 + ri * 32 + 4 * fk16;
        #pragma unroll
        for (int cj = 0; cj < 2; ++cj) {
            if (!nok[cj]) continue;
            #pragma unroll
            for (int r = 0; r < 16; ++r) {
                int v = vbase + (r & 3) + 8 * (r >> 2);
                if (v < V_) {
                    float val = acc[ri][cj][r] * INV24 + biasv[cj];
                    cw[(size_t)v * CWS + ncol[cj]] = fmaxf(logsigf(val), lwv[cj]);
                }
            }
        }
    }
}

// ---------------- f32 fallback (round-2 kernel) ----------------

__global__ __launch_bounds__(256) void k1_gemm_cw(
    const float* __restrict__ emb,
    const float* __restrict__ diags,
    const float* __restrict__ bias,
    const float* __restrict__ wildc,
    float* __restrict__ cw)
{
    __shared__ float As[BK][LDP];
    __shared__ float Bs[BK][LDP];

    const int tid = threadIdx.x;
    const int v0 = blockIdx.x * BM;
    const int n0 = blockIdx.y * BN;
    const int tx = tid & 15;
    const int ty = tid >> 4;

    float acc[8][8];
    #pragma unroll
    for (int i = 0; i < 8; ++i)
        #pragma unroll
        for (int j = 0; j < 8; ++j) acc[i][j] = 0.f;

    const int a_k = tid >> 4;
    const int a_v = (tid & 15) * 8;
    const int b_n   = tid >> 1;
    const int b_kof = (tid & 1) * 8;

    int  brow;
    bool bval;
    {
        int n = n0 + b_n;
        bval = (n < NOUT);
        brow = bval ? ((n / 5) * 6 + (n % 5)) : 0;
    }

    for (int k0 = 0; k0 < KDIM; k0 += BK) {
        {
            float4 f0 = {0,0,0,0}, f1 = {0,0,0,0};
            int k = k0 + a_k;
            if (k < KDIM) {
                const float* src = emb + (size_t)k * V_ + v0 + a_v;
                if (v0 + a_v + 3 < V_) f0 = *(const float4*)src;
                if (v0 + a_v + 7 < V_) f1 = *(const float4*)(src + 4);
            }
            *(float4*)&As[a_k][a_v]     = f0;
            *(float4*)&As[a_k][a_v + 4] = f1;
        }
        {
            float4 f = {0,0,0,0}, g = {0,0,0,0};
            if (bval) {
                const float* src = diags + (size_t)brow * KDIM + k0 + b_kof;
                if (k0 + b_kof + 3 < KDIM) f = *(const float4*)src;
                if (k0 + b_kof + 7 < KDIM) g = *(const float4*)(src + 4);
            }
            Bs[b_kof + 0][b_n] = f.x;
            Bs[b_kof + 1][b_n] = f.y;
            Bs[b_kof + 2][b_n] = f.z;
            Bs[b_kof + 3][b_n] = f.w;
            Bs[b_kof + 4][b_n] = g.x;
            Bs[b_kof + 5][b_n] = g.y;
            Bs[b_kof + 6][b_n] = g.z;
            Bs[b_kof + 7][b_n] = g.w;
        }
        __syncthreads();
        #pragma unroll
        for (int k = 0; k < BK; ++k) {
            float4 a0 = *(const float4*)&As[k][tx * 4];
            float4 a1 = *(const float4*)&As[k][64 + tx * 4];
            float4 b0 = *(const float4*)&Bs[k][ty * 8];
            float4 b1 = *(const float4*)&Bs[k][ty * 8 + 4];
            float av[8] = {a0.x, a0.y, a0.z, a0.w, a1.x, a1.y, a1.z, a1.w};
            float bv[8] = {b0.x, b0.y, b0.z, b0.w, b1.x, b1.y, b1.z, b1.w};
            #pragma unroll
            for (int i = 0; i < 8; ++i)
                #pragma unroll
                for (int j = 0; j < 8; ++j)
                    acc[i][j] = fmaf(av[i], bv[j], acc[i][j]);
        }
        __syncthreads();
    }

    float biasv[8], lwv[8];
    #pragma unroll
    for (int j = 0; j < 8; ++j) {
        int n  = n0 + ty * 8 + j;
        int nc = (n < NOUT) ? n : 0;
        int pm = (nc / 5) * 6 + (nc % 5);
        biasv[j] = bias[pm];
        lwv[j]   = logsigf(wildc[nc]);
    }
    #pragma unroll
    for (int i = 0; i < 8; ++i) {
        int v = v0 + ((i < 4) ? (tx * 4 + i) : (64 + tx * 4 + (i - 4)));
        if (v >= V_) continue;
        float r[8];
        #pragma unroll
        for (int j = 0; j < 8; ++j)
            r[j] = fmaxf(logsigf(acc[i][j] + biasv[j]), lwv[j]);
        float* dst = cw + (size_t)v * CWS + n0 + ty * 8;
        if (n0 + ty * 8     < NOUT) *(float4*)dst       = make_float4(r[0], r[1], r[2], r[3]);
        if (n0 + ty * 8 + 4 < NOUT) *(float4*)(dst + 4) = make_float4(r[4], r[5], r[6], r[7]);
    }
}

// ---------------- scan + finalize (unchanged) ----------------

__global__ __launch_bounds__(192) void k2_scan(
    const int* __restrict__ docs,
    const int* __restrict__ doc_lens,
    const float* __restrict__ cw,
    float* __restrict__ cs)
{
    const int ci = blockIdx.x;
    const int b  = blockIdx.y;
    const int t0 = ci * TCHUNK;
    const int ts = (t0 >= WARM) ? (t0 - WARM) : 0;
    const int dl = doc_lens[b];
    const int te = min(t0 + TCHUNK, dl);
    const int nt = te - ts;

    __shared__ int toks[TCHUNK + WARM];
    if (threadIdx.x < TCHUNK + WARM) {
        int t = ts + threadIdx.x;
        toks[threadIdx.x] = docs[b * L_ + min(t, L_ - 1)];
    }
    __syncthreads();

    const int p = threadIdx.x;
    float sc = NEGF;
    if (p < P_) {
        const float* basep = cw + p * 5;
        const int e = (p < 50) ? 3 : (p < 100) ? 4 : 5;
        float h1 = NEGF, h2 = NEGF, h3 = NEGF, h4 = NEGF, h5 = NEGF;
        const int warm_n = t0 - ts;
        #pragma unroll 4
        for (int i = 0; i < nt; ++i) {
            const float* cp = basep + (size_t)toks[i] * CWS;
            float c0 = cp[0], c1 = cp[1], c2 = cp[2], c3 = cp[3], c4 = cp[4];
            h5 = h4 + c4;
            h4 = h3 + c3;
            h3 = h2 + c2;
            h2 = h1 + c1;
            h1 = c0;
            if (i >= warm_n) {
                float esv = (e == 3) ? h3 : (e == 4) ? h4 : h5;
                sc = fmaxf(sc, esv);
            }
        }
    }
    if (p < P_) cs[(size_t)(b * NCHUNK + ci) * CS_STRIDE + p] = sc;
}

__device__ __forceinline__ float block_sum192(float v, volatile float* red, int tid) {
    #pragma unroll
    for (int off = 32; off > 0; off >>= 1) v += __shfl_down(v, off, 64);
    __syncthreads();
    if ((tid & 63) == 0) red[tid >> 6] = v;
    __syncthreads();
    return red[0] + red[1] + red[2];
}

__global__ __launch_bounds__(192) void k3_final(
    const float* __restrict__ cs,
    const float* __restrict__ gamma,
    const float* __restrict__ beta,
    const float* __restrict__ lw,
    const float* __restrict__ lb,
    float* __restrict__ out)
{
    __shared__ float red[3];
    const int b   = blockIdx.x;
    const int tid = threadIdx.x;
    float s = 0.f;
    if (tid < P_) {
        float m = NEGF;
        const float* row = cs + (size_t)b * NCHUNK * CS_STRIDE + tid;
        #pragma unroll
        for (int ci = 0; ci < NCHUNK; ++ci) m = fmaxf(m, row[ci * CS_STRIDE]);
        s = expf(m);
    }
    float mu = block_sum192(s, red, tid) * (1.f / P_);
    float d  = (tid < P_) ? (s - mu) : 0.f;
    float var = block_sum192(d * d, red, tid) * (1.f / P_);
    float bin = 0.f;
    if (tid < P_) {
        float norm = (s - mu) * rsqrtf(var + 1e-5f) * gamma[tid] + beta[tid];
        bin = (norm > 0.f) ? 1.f : 0.f;
    }
    float o0 = block_sum192((tid < P_) ? bin * lw[tid]      : 0.f, red, tid);
    float o1 = block_sum192((tid < P_) ? bin * lw[P_ + tid] : 0.f, red, tid);
    if (tid == 0) {
        out[b * 2 + 0] = o0 + lb[0];
        out[b * 2 + 1] = o1 + lb[1];
    }
}

extern "C" void kernel_launch(void* const* d_in, const int* in_sizes, int n_in,
                              void* d_out, int out_size, void* d_ws, size_t ws_size,
                              hipStream_t stream)
{
    const int*   docs  = (const int*)  d_in[0];
    const int*   dlens = (const int*)  d_in[1];
    const float* emb   = (const float*)d_in[2];
    const float* diags = (const float*)d_in[3];
    const float* bias  = (const float*)d_in[4];
    const float* wildc = (const float*)d_in[5];
    const float* gamma = (const float*)d_in[6];
    const float* beta  = (const float*)d_in[7];
    const float* lw    = (const float*)d_in[8];
    const float* lb    = (const float*)d_in[9];
    float* out = (float*)d_out;

    // ws layout: cw | cs | a1 | a2 | b1 | b2
    const size_t cw_b = (size_t)V_ * CWS * 4;          // 60,160,000
    const size_t cs_b = (size_t)B_ * NCHUNK * CS_STRIDE * 4;
    const size_t a_b  = (size_t)V_ * KP * 2;           // 12,800,000 each
    const size_t bb_b = (size_t)NP * KP * 2;           // 491,520 each
    const size_t need = cw_b + cs_b + 2 * a_b + 2 * bb_b;

    char* base = (char*)d_ws;
    float*  cw = (float*)base;
    float*  cs = (float*)(base + cw_b);
    ushort* a1 = (ushort*)(base + cw_b + cs_b);
    ushort* a2 = (ushort*)(base + cw_b + cs_b + a_b);
    ushort* b1 = (ushort*)(base + cw_b + cs_b + 2 * a_b);
    ushort* b2 = (ushort*)(base + cw_b + cs_b + 2 * a_b + bb_b);

    if (ws_size >= need) {
        p1_split_a<<<dim3((V_ + 63) / 64, KP / 64), 256, 0, stream>>>(emb, a1, a2);
        p2_split_b<<<NP, 64, 0, stream>>>(diags, b1, b2);
        k1m_gemm<<<dim3((V_ + 127) / 128, NP / 128), 256, 0, stream>>>(
            a1, a2, b1, b2, bias, wildc, cw);
    } else {
        dim3 g1((V_ + BM - 1) / BM, (NOUT + BN - 1) / BN);
        k1_gemm_cw<<<g1, 256, 0, stream>>>(emb, diags, bias, wildc, cw);
    }

    dim3 g2(NCHUNK, B_);
    k2_scan<<<g2, 192, 0, stream>>>(docs, dlens, cw, cs);
    k3_final<<<B_, 192, 0, stream>>>(cs, gamma, beta, lw, lb, out);
}